// Round 7
// baseline (2031.283 us; speedup 1.0000x reference)
//
#include <hip/hip_runtime.h>

// ConvLstm (B=64, S=256, H=1024, fp32 in/out) — fused persistent kernel, round 7.
//
// Round-6 post-mortem: killing acquire/release L2 storms gave 4440->1850 us,
// but the per-step counting barrier is a serial chain of contended coherence-
// point round trips (store-ack -> 64 serialized same-line atomic RMWs -> poll
// detect -> h load) ~= 17 K cyc/step with all pipes idle.
//
// Round 7: NO barrier at all. h is stored as tagged u32 (h_fp16<<16 | step_tag);
// producers fire-and-forget (no ack/flag/atomic); each consumer wave polls its
// own fragment region with sc0 sc1 loads until every entry's tag == t — the
// successful poll IS the data load. Chain = store-visible + one poll RT.
// Safety: ping-pong + tags. A WG writes h_{t+1} only after fully reading h_t;
// h_t complete => all WGs finished reading h_{t-1} (program order), so the
// parity buffer being overwritten has no remaining readers. 0xAA poison
// (tag 0xAAAA) never matches tags in [0,256].
//
// Structure: 256 WGs x 256 threads, 1 WG/CU, co-resident (plain launch).
//   4 clusters x 64 WGs; cluster owns 16 batches; WG slot owns 16 channels x
//   4 gates; wave w owns K in [256w,256w+256). Wh/Wx fp16 fragments in VGPRs.
//   x-side MFMAs for step t+1 + LDS staging of x[t+2] run after h_t is stored
//   (hidden behind the next poll wait).
//
// ws layout: [0, 524288) tagged h ping-pong buffer u32[2][64][1024].

#define S_LEN 256
#define H_DIM 1024
#define B_DIM 64

typedef _Float16 v8h __attribute__((ext_vector_type(8)));
typedef float v4f __attribute__((ext_vector_type(4)));
typedef unsigned v4u __attribute__((ext_vector_type(4)));

__device__ __forceinline__ v8h pack8h(float4 a, float4 b) {
  v8h r;
  r[0] = (_Float16)a.x; r[1] = (_Float16)a.y; r[2] = (_Float16)a.z; r[3] = (_Float16)a.w;
  r[4] = (_Float16)b.x; r[5] = (_Float16)b.y; r[6] = (_Float16)b.z; r[7] = (_Float16)b.w;
  return r;
}

__device__ __forceinline__ float fsigmoid(float x) { return 1.0f / (1.0f + __expf(-x)); }
__device__ __forceinline__ float ftanh(float x) {
  float e = __expf(2.0f * x);          // +inf for large x is fine: 2/(inf+1)=0
  return 1.0f - 2.0f / (e + 1.0f);
}

__global__ void k_init(const float* __restrict__ h0,
                       unsigned* __restrict__ hbuf) {
  int i = blockIdx.x * 256 + threadIdx.x;
  // parity 0 holds h0 with tag 0 (consumed at step 0)
  for (int idx = i; idx < B_DIM * H_DIM; idx += gridDim.x * 256) {
    _Float16 h = (_Float16)h0[idx];
    hbuf[idx] = ((unsigned)__builtin_bit_cast(unsigned short, h) << 16) | 0u;
  }
  // end-of-dispatch release flushes L2 to the coherence point, so lstm_fused's
  // sc0 sc1 bypass loads observe these tags.
}

__global__ __launch_bounds__(256, 1) void lstm_fused(
    const float* __restrict__ x, const float* __restrict__ Wx,
    const float* __restrict__ Wh, const float* __restrict__ c0,
    const float* __restrict__ bx, const float* __restrict__ bh,
    const float* __restrict__ bgate, const float* __restrict__ peep,
    unsigned* __restrict__ hbuf, float* __restrict__ out) {
  __shared__ float pre[4][4][16][18];          // pad 18: store pattern 2-way (free)
  __shared__ _Float16 ldsx[16 * 1032];         // [batch][k] fp16, padded rows

  const int tid = threadIdx.x;
  const int wid = tid >> 6;                    // wave id = K-range owner
  const int lane = tid & 63;
  const int la = lane & 15;                    // MFMA: A-row (batch) / B-col (chan)
  const int lq = lane >> 4;
  const int cluster = blockIdx.x >> 6;         // 4 clusters x 64 WGs
  const int slot = blockIdx.x & 63;
  const int ch0 = slot * 16;                   // this WG's channel slice
  const int b0 = cluster * 16;                 // this cluster's batch slice

  // ---- one-time: weight fragments into VGPRs (fp16 B-operand layout:
  // lane holds B[k = lq*8 + j][n = la]; MFMA kk covers k in [kk*32, kk*32+32)) ----
  v8h wh_f[4][8], wx_f[4][8];
  {
    const int col = wid * 256 + lq * 8;
#pragma unroll
    for (int g = 0; g < 4; ++g) {
#pragma unroll
      for (int kk = 0; kk < 8; ++kk) {
        const float* ph = Wh + (size_t)(g * 1024 + ch0 + la) * 1024 + col + kk * 32;
        wh_f[g][kk] = pack8h(*(const float4*)ph, *(const float4*)(ph + 4));
        const float* px = Wx + (size_t)(g * 1024 + ch0 + la) * 1024 + col + kk * 32;
        wx_f[g][kk] = pack8h(*(const float4*)px, *(const float4*)(px + 4));
      }
    }
  }

  // ---- elementwise-thread constants (thread <-> (batch bl, chan nn)) ----
  const int bl = tid >> 4;
  const int nn = tid & 15;
  const int gb = b0 + bl;                      // global batch
  const int ch = ch0 + nn;                     // global channel
  float bias_c[4];
#pragma unroll
  for (int g = 0; g < 4; ++g)
    bias_c[g] = bx[g * 1024 + ch] + bh[g * 1024 + ch] + bgate[g * 1024 + ch];
  const float pI = peep[ch], pF = peep[1024 + ch], pO = peep[2048 + ch];
  float c_st = c0[gb * 1024 + ch];             // cell state lives in a register

  auto stage = [&](int ts) {                   // x[:, ts, :] (cluster batches) -> LDS fp16
#pragma unroll
    for (int j = 0; j < 8; ++j) {
      int cid = tid + j * 256;                 // 2048 chunks of 8 floats
      int row = cid >> 7, c8 = cid & 127;
      const float* px = x + (size_t)(b0 + row) * (S_LEN * H_DIM) + (size_t)ts * H_DIM + c8 * 8;
      *(v8h*)(&ldsx[row * 1032 + c8 * 8]) = pack8h(*(const float4*)px, *(const float4*)(px + 4));
    }
  };
  const v4f vzero = {0.f, 0.f, 0.f, 0.f};
  v4f acc[4];
  auto xmfma = [&]() {                         // 32 x-side MFMAs from ldsx
#pragma unroll
    for (int kk = 0; kk < 8; ++kk) {
      v8h ax = *(const v8h*)(&ldsx[la * 1032 + wid * 256 + kk * 32 + lq * 8]);
#pragma unroll
      for (int g = 0; g < 4; ++g)
        acc[g] = __builtin_amdgcn_mfma_f32_16x16x32_f16(ax, wx_f[g][kk], acc[g], 0, 0, 0);
    }
  };

  // ---- prologue: x-partials for step 0, then stage x[1] ----
  stage(0);
  __syncthreads();
#pragma unroll
  for (int g = 0; g < 4; ++g) acc[g] = vzero;
  xmfma();
  __syncthreads();                             // everyone done reading x[0]
  stage(1);

  for (int t = 0; t < S_LEN; ++t) {
    // ---- poll-load h_{t-1} (tag t) from parity t&1; the poll IS the load ----
    const unsigned* hb = hbuf + (t & 1) * (B_DIM * H_DIM) +
                         (size_t)(b0 + la) * H_DIM + wid * 256 + lq * 8;
    v4u u0, u1, u2, u3, u4, u5, u6, u7, u8, u9, ua, ub, uc, ud, ue, uf;
    const unsigned tag = (unsigned)t;
    for (;;) {
      asm volatile(
          "global_load_dwordx4 %0, %[p], off sc0 sc1\n\t"
          "global_load_dwordx4 %1, %[p], off offset:16 sc0 sc1\n\t"
          "global_load_dwordx4 %2, %[p], off offset:128 sc0 sc1\n\t"
          "global_load_dwordx4 %3, %[p], off offset:144 sc0 sc1\n\t"
          "global_load_dwordx4 %4, %[p], off offset:256 sc0 sc1\n\t"
          "global_load_dwordx4 %5, %[p], off offset:272 sc0 sc1\n\t"
          "global_load_dwordx4 %6, %[p], off offset:384 sc0 sc1\n\t"
          "global_load_dwordx4 %7, %[p], off offset:400 sc0 sc1\n\t"
          "global_load_dwordx4 %8, %[p], off offset:512 sc0 sc1\n\t"
          "global_load_dwordx4 %9, %[p], off offset:528 sc0 sc1\n\t"
          "global_load_dwordx4 %10, %[p], off offset:640 sc0 sc1\n\t"
          "global_load_dwordx4 %11, %[p], off offset:656 sc0 sc1\n\t"
          "global_load_dwordx4 %12, %[p], off offset:768 sc0 sc1\n\t"
          "global_load_dwordx4 %13, %[p], off offset:784 sc0 sc1\n\t"
          "global_load_dwordx4 %14, %[p], off offset:896 sc0 sc1\n\t"
          "global_load_dwordx4 %15, %[p], off offset:912 sc0 sc1\n\t"
          "s_waitcnt vmcnt(0)"
          : "=&v"(u0), "=&v"(u1), "=&v"(u2), "=&v"(u3),
            "=&v"(u4), "=&v"(u5), "=&v"(u6), "=&v"(u7),
            "=&v"(u8), "=&v"(u9), "=&v"(ua), "=&v"(ub),
            "=&v"(uc), "=&v"(ud), "=&v"(ue), "=&v"(uf)
          : [p] "v"(hb)
          : "memory");
      unsigned bad = 0;
#define CHK(U) bad |= ((U[0] ^ tag) | (U[1] ^ tag) | (U[2] ^ tag) | (U[3] ^ tag)) & 0xFFFFu
      CHK(u0); CHK(u1); CHK(u2); CHK(u3); CHK(u4); CHK(u5); CHK(u6); CHK(u7);
      CHK(u8); CHK(u9); CHK(ua); CHK(ub); CHK(uc); CHK(ud); CHK(ue); CHK(uf);
#undef CHK
      if (__all(bad == 0)) break;
      __builtin_amdgcn_s_sleep(1);
    }
    // extract fp16 halves (high 16 bits of each entry) -> A-fragments
    v8h ah[8];
    {
      v4u lo, hi, pk;
#define PACK(KK, LO, HI)                                                    \
      lo = LO; hi = HI;                                                     \
      pk[0] = (lo[0] >> 16) | (lo[1] & 0xFFFF0000u);                        \
      pk[1] = (lo[2] >> 16) | (lo[3] & 0xFFFF0000u);                        \
      pk[2] = (hi[0] >> 16) | (hi[1] & 0xFFFF0000u);                        \
      pk[3] = (hi[2] >> 16) | (hi[3] & 0xFFFF0000u);                        \
      ah[KK] = __builtin_bit_cast(v8h, pk)
      PACK(0, u0, u1); PACK(1, u2, u3); PACK(2, u4, u5); PACK(3, u6, u7);
      PACK(4, u8, u9); PACK(5, ua, ub); PACK(6, uc, ud); PACK(7, ue, uf);
#undef PACK
    }
#pragma unroll
    for (int kk = 0; kk < 8; ++kk) {
#pragma unroll
      for (int g = 0; g < 4; ++g)
        acc[g] = __builtin_amdgcn_mfma_f32_16x16x32_f16(ah[kk], wh_f[g][kk], acc[g], 0, 0, 0);
    }

    // publish wave partials: D layout col=lane&15, row=(lane>>4)*4+reg
#pragma unroll
    for (int g = 0; g < 4; ++g)
#pragma unroll
      for (int r = 0; r < 4; ++r)
        pre[wid][g][lq * 4 + r][la] = acc[g][r];
    __syncthreads();

    // elementwise gates (thread = one (batch, channel))
    float s[4];
#pragma unroll
    for (int g = 0; g < 4; ++g)
      s[g] = pre[0][g][bl][nn] + pre[1][g][bl][nn] + pre[2][g][bl][nn] +
             pre[3][g][bl][nn] + bias_c[g];
    float ig = fsigmoid(s[0] + pI * c_st);
    float fg = fsigmoid(s[1] + pF * c_st);
    float cn = fg * c_st + ig + ftanh(s[2]);   // NOTE: +ig (reference quirk), not ig*tanh
    float og = fsigmoid(s[3] + pO * cn);
    float hn = og * ftanh(cn);
    c_st = cn;

    // tagged h store: fire-and-forget to the coherence point (no ack needed —
    // consumers poll the tag). parity (t+1)&1, tag t+1.
    {
      unsigned* hp = hbuf + ((t + 1) & 1) * (B_DIM * H_DIM) + gb * H_DIM + ch;
      unsigned hv = ((unsigned)__builtin_bit_cast(unsigned short, (_Float16)hn) << 16) |
                    (unsigned)(t + 1);
      asm volatile(
          "global_store_dword %[p], %[d], off sc0 sc1"
          :: [p] "v"(hp), [d] "v"(hv)
          : "memory");
    }
    out[((size_t)gb * S_LEN + t) * H_DIM + ch] = hn;

    if (t < S_LEN - 1) {
      // off the critical path: x-partials for step t+1, then stage x[t+2]
#pragma unroll
      for (int g = 0; g < 4; ++g) acc[g] = vzero;
      xmfma();                                 // reads ldsx == x[t+1]
      __syncthreads();                         // everyone done reading x[t+1]
      int tn = t + 2 < S_LEN ? t + 2 : S_LEN - 1;
      stage(tn);                               // next pre-exchange barrier orders reads
    }
  }
}

extern "C" void kernel_launch(void* const* d_in, const int* in_sizes, int n_in,
                              void* d_out, int out_size, void* d_ws, size_t ws_size,
                              hipStream_t stream) {
  (void)in_sizes; (void)n_in; (void)out_size; (void)ws_size;
  const float* x    = (const float*)d_in[0];
  const float* h0   = (const float*)d_in[1];
  const float* c0   = (const float*)d_in[2];
  const float* Wx   = (const float*)d_in[3];
  const float* bx   = (const float*)d_in[4];
  const float* Wh   = (const float*)d_in[5];
  const float* bh   = (const float*)d_in[6];
  const float* peep = (const float*)d_in[7];
  const float* bg   = (const float*)d_in[8];
  float* out = (float*)d_out;

  unsigned* hbuf = (unsigned*)d_ws;            // u32[2][64][1024] = 512 KB

  k_init<<<64, 256, 0, stream>>>(h0, hbuf);
  lstm_fused<<<256, 256, 0, stream>>>(x, Wx, Wh, c0, bx, bh, bg, peep,
                                      hbuf, out);
}